// Round 8
// baseline (73.311 us; speedup 1.0000x reference)
//
#include <hip/hip_runtime.h>

// Problem constants (reference: B=2, N=2048, DIM=512, H=8, DH=64)
constexpr int kB   = 2;
constexpr int kN   = 2048;
constexpr int kDIM = 512;
constexpr int kH   = 8;
constexpr int kDH  = 64;
constexpr int kBH  = kB * kH;          // 16
constexpr int NROWS = kB * kN;         // 4096
constexpr int CHUNK = 64;
constexpr int NCH   = kN / CHUNK;      // 32
constexpr int CBSTRIDE = kDH * kDH + kDH;  // 4160 per (bh,chunk): ST[e][d] (4096) + z (64)
constexpr float kEPS = 1e-3f;

typedef _Float16 f16x8 __attribute__((ext_vector_type(8)));
typedef _Float16 f16x4 __attribute__((ext_vector_type(4)));
typedef float    floatx4 __attribute__((ext_vector_type(4)));

__device__ __forceinline__ void async_copy16(void* lds, const void* g) {
    __builtin_amdgcn_global_load_lds(
        (const __attribute__((address_space(1))) void*)g,
        (__attribute__((address_space(3))) void*)lds,
        16, 0, 0);
}

// ---------------------------------------------------------------------------
// Prep: z=0..3 -> weight transpose+convert (Wq,Wk,Wv -> WT[1536][512], Wo -> WoT);
//       z=4..11 -> x fp32 -> fp16 straight convert (strided strips).
// grid (16,16,12), block 256.
// ---------------------------------------------------------------------------
__global__ __launch_bounds__(256)
void prep_kernel(const float* __restrict__ Wq, const float* __restrict__ Wk,
                 const float* __restrict__ Wv, const float* __restrict__ Wo,
                 const float* __restrict__ x,
                 _Float16* __restrict__ WT, _Float16* __restrict__ WoT,
                 _Float16* __restrict__ xh)
{
    const int z = blockIdx.z;
    if (z >= 4) {
        const size_t base = (((size_t)(z - 4) * 256 + blockIdx.y * 16 + blockIdx.x) * 256 +
                             threadIdx.x) * 4;
        const float4 a = *(const float4*)(x + base);
        f16x4 o;
        o[0] = (_Float16)a.x; o[1] = (_Float16)a.y;
        o[2] = (_Float16)a.z; o[3] = (_Float16)a.w;
        *(f16x4*)(xh + base) = o;
        return;
    }
    __shared__ float tile[32][33];
    const float* src = (z == 0) ? Wq : (z == 1) ? Wk : (z == 2) ? Wv : Wo;
    _Float16* dst = (z < 3) ? (WT + (size_t)z * 512 * 512) : WoT;
    const int r0 = blockIdx.y * 32, c0 = blockIdx.x * 32;
    const int tr = threadIdx.x >> 5, tc = threadIdx.x & 31;
    #pragma unroll
    for (int i = 0; i < 4; ++i)
        tile[tr + 8 * i][tc] = src[(size_t)(r0 + tr + 8 * i) * 512 + c0 + tc];
    __syncthreads();
    #pragma unroll
    for (int i = 0; i < 4; ++i)
        dst[(size_t)(c0 + tr + 8 * i) * 512 + r0 + tc] = (_Float16)tile[tc][tr + 8 * i];
}

// ---------------------------------------------------------------------------
// qkv MFMA GEMM.  BM=128, BN=256, BK=64, 512 threads (8 waves, 2m x 4n).
// A (xh f16) and B (WT f16) via global_load_lds, XOR-swizzled source+read.
// Epilogue -> fp16 qh,khb row-major [bh][n][64] (relu+eps on q,k),
//             fp16 kTh,vTh transposed [bh][d][n].
// grid (6, 32).
// ---------------------------------------------------------------------------
__global__ __launch_bounds__(512)
void qkv_gemm_kernel(const _Float16* __restrict__ A,
                     const _Float16* __restrict__ BT,
                     _Float16* __restrict__ qh,
                     _Float16* __restrict__ khb,
                     _Float16* __restrict__ kTh,
                     _Float16* __restrict__ vTh)
{
    constexpr int K = 512;
    __shared__ _Float16 As[128 * 64];   // 16 KB, rows of 128 B, swizzled
    __shared__ _Float16 Bs[256 * 64];   // 32 KB

    const int t = threadIdx.x;
    const int l = t & 63;
    const int w = t >> 6;               // 0..7
    const int wm = w >> 2, wn = w & 3;  // 2 x 4 wave grid
    const int m0 = blockIdx.y * 128;
    const int n0 = blockIdx.x * 256;

    const int r15 = l & 15, kq = l >> 4, sw = r15 & 7;

    floatx4 acc[4][4];
    #pragma unroll
    for (int mi = 0; mi < 4; ++mi)
        #pragma unroll
        for (int ni = 0; ni < 4; ++ni)
            acc[mi][ni] = (floatx4){0.f, 0.f, 0.f, 0.f};

    const char* Abase = (const char*)(A + (size_t)m0 * K);
    const char* Bbase = (const char*)(BT + (size_t)n0 * K);
    char* AsB = (char*)As;
    char* BsB = (char*)Bs;

    const char* ArdB = (const char*)As + (wm * 64 + r15) * 128;
    const char* BrdB = (const char*)Bs + (wn * 64 + r15) * 128;
    const int sw0 = ((kq ^ sw) << 4);
    const int sw1 = (((4 + kq) ^ sw) << 4);

    for (int k0 = 0; k0 < K; k0 += 64) {
        // A tile: 1024 16B-slots, 2 rounds of 512 threads
        #pragma unroll
        for (int i = 0; i < 2; ++i) {
            const int s = i * 512 + t;
            const int row = s >> 3, sl = s & 7;
            const int gsl = sl ^ (row & 7);
            async_copy16(AsB + row * 128 + sl * 16,
                         Abase + (size_t)row * (K * 2) + k0 * 2 + gsl * 16);
        }
        // B tile: 2048 16B-slots, 4 rounds
        #pragma unroll
        for (int i = 0; i < 4; ++i) {
            const int s = i * 512 + t;
            const int row = s >> 3, sl = s & 7;
            const int gsl = sl ^ (row & 7);
            async_copy16(BsB + row * 128 + sl * 16,
                         Bbase + (size_t)row * (K * 2) + k0 * 2 + gsl * 16);
        }
        __syncthreads();

        f16x8 af[4][2], bf[4][2];
        #pragma unroll
        for (int i = 0; i < 4; ++i) {
            af[i][0] = *(const f16x8*)(ArdB + i * 2048 + sw0);
            af[i][1] = *(const f16x8*)(ArdB + i * 2048 + sw1);
            bf[i][0] = *(const f16x8*)(BrdB + i * 2048 + sw0);
            bf[i][1] = *(const f16x8*)(BrdB + i * 2048 + sw1);
        }
        #pragma unroll
        for (int kk = 0; kk < 2; ++kk)
            #pragma unroll
            for (int mi = 0; mi < 4; ++mi)
                #pragma unroll
                for (int ni = 0; ni < 4; ++ni)
                    acc[mi][ni] = __builtin_amdgcn_mfma_f32_16x16x32_f16(
                        af[mi][kk], bf[ni][kk], acc[mi][ni], 0, 0, 0);
        __syncthreads();
    }

    // Epilogue.  C fragment: row = kq*4 + r, col = r15 (within each 16x16).
    #pragma unroll
    for (int ni = 0; ni < 4; ++ni) {
        const int col = n0 + wn * 64 + ni * 16 + r15;   // 0..1535
        const int which = col >> 9;
        const int h = (col >> 6) & 7, e = col & 63;
        #pragma unroll
        for (int mi = 0; mi < 4; ++mi) {
            const int row0 = m0 + wm * 64 + mi * 16 + kq * 4;
            const int b = row0 >> 11, nn = row0 & 2047;
            const int bh = b * 8 + h;
            float vv[4];
            #pragma unroll
            for (int r = 0; r < 4; ++r) {
                float v = acc[mi][ni][r];
                if (which < 2) v = fmaxf(v, 0.f) + kEPS;
                vv[r] = v;
            }
            if (which == 0) {
                #pragma unroll
                for (int r = 0; r < 4; ++r)
                    qh[((size_t)bh * kN + nn + r) * 64 + e] = (_Float16)vv[r];
            } else if (which == 1) {
                #pragma unroll
                for (int r = 0; r < 4; ++r)
                    khb[((size_t)bh * kN + nn + r) * 64 + e] = (_Float16)vv[r];
                f16x4 t4;
                t4[0] = (_Float16)vv[0]; t4[1] = (_Float16)vv[1];
                t4[2] = (_Float16)vv[2]; t4[3] = (_Float16)vv[3];
                *(f16x4*)(kTh + ((size_t)bh * 64 + e) * kN + nn) = t4;
            } else {
                f16x4 t4;
                t4[0] = (_Float16)vv[0]; t4[1] = (_Float16)vv[1];
                t4[2] = (_Float16)vv[2]; t4[3] = (_Float16)vv[3];
                *(f16x4*)(vTh + ((size_t)bh * 64 + e) * kN + nn) = t4;
            }
        }
    }
}

// ---------------------------------------------------------------------------
// Fused chunk-sum + exclusive-prefix scan.  The MFMA accumulator IS the
// running prefix: per chunk, store acc (exclusive ST_pre, fp16), then
// acc += v_ch^T k_ch via MFMA.  z cumsum via ones-A MFMA (wave 0).
// grid (2 d-halves, 16 bh), block 256 (4 waves = 64 e-rows), no LDS.
// ---------------------------------------------------------------------------
__global__ __launch_bounds__(256)
void scan_kernel(const _Float16* __restrict__ kTh, const _Float16* __restrict__ vTh,
                 _Float16* __restrict__ spre16, float* __restrict__ zpre)
{
    const int dh = blockIdx.x;       // 0..1: d-cols dh*32 .. dh*32+31
    const int bh = blockIdx.y;       // 0..15
    const int t = threadIdx.x, l = t & 63, w = t >> 6;
    const int r15 = l & 15, kq = l >> 4;

    const _Float16* vbase = vTh + (size_t)bh * 64 * kN;   // [e][n]
    const _Float16* kbase = kTh + (size_t)bh * 64 * kN;   // [d][n]

    floatx4 acc[2];   // running ST prefix: row e = w*16+kq*4+r, col d = dh*32+ni*16+r15
    acc[0] = (floatx4){0.f, 0.f, 0.f, 0.f};
    acc[1] = (floatx4){0.f, 0.f, 0.f, 0.f};
    floatx4 zacc[2];  // running z (wave 0 only)
    zacc[0] = (floatx4){0.f, 0.f, 0.f, 0.f};
    zacc[1] = (floatx4){0.f, 0.f, 0.f, 0.f};

    f16x8 ones;
    #pragma unroll
    for (int u = 0; u < 8; ++u) ones[u] = (_Float16)1.0f;

    for (int ch = 0; ch < NCH; ++ch) {
        // store exclusive prefix (before update)
        _Float16* sp = spre16 + ((size_t)bh * NCH + ch) * CBSTRIDE;
        #pragma unroll
        for (int ni = 0; ni < 2; ++ni)
            #pragma unroll
            for (int r = 0; r < 4; ++r)
                sp[(size_t)(w * 16 + kq * 4 + r) * 64 + dh * 32 + ni * 16 + r15] =
                    (_Float16)acc[ni][r];
        if (w == 0 && kq == 0) {
            float* zp = zpre + ((size_t)bh * NCH + ch) * 64 + dh * 32;
            zp[r15]      = zacc[0][0];
            zp[16 + r15] = zacc[1][0];
        }
        // load this chunk's fragments (identical bk across waves; av differs by w)
        f16x8 av[2], bk[2][2];
        #pragma unroll
        for (int kk = 0; kk < 2; ++kk) {
            av[kk] = *(const f16x8*)(vbase + (size_t)(w * 16 + r15) * kN +
                                     ch * 64 + kk * 32 + kq * 8);
            #pragma unroll
            for (int ni = 0; ni < 2; ++ni)
                bk[ni][kk] = *(const f16x8*)(kbase + (size_t)(dh * 32 + ni * 16 + r15) * kN +
                                             ch * 64 + kk * 32 + kq * 8);
        }
        // state update: acc += v^T k  (C accumulate = the scan)
        #pragma unroll
        for (int kk = 0; kk < 2; ++kk)
            #pragma unroll
            for (int ni = 0; ni < 2; ++ni)
                acc[ni] = __builtin_amdgcn_mfma_f32_16x16x32_f16(av[kk], bk[ni][kk], acc[ni], 0, 0, 0);
        if (w == 0) {
            #pragma unroll
            for (int kk = 0; kk < 2; ++kk)
                #pragma unroll
                for (int ni = 0; ni < 2; ++ni)
                    zacc[ni] = __builtin_amdgcn_mfma_f32_16x16x32_f16(ones, bk[ni][kk], zacc[ni], 0, 0, 0);
        }
    }
}

// ---------------------------------------------------------------------------
// chunk_out (MFMA): scores = QK^T (masked) -> P fp16 in swizzled LDS,
// O = P V + Q STpre, den = rowsum(P) + q.z_pre, attn = O/den (fp16).
// grid (NCH, BH), block 256 (wave w = query rows w*16..w*16+15).
// ---------------------------------------------------------------------------
__global__ __launch_bounds__(256)
void chunk_out_kernel(const _Float16* __restrict__ qh, const _Float16* __restrict__ khb,
                      const _Float16* __restrict__ vTh, const _Float16* __restrict__ spre16,
                      const float* __restrict__ zpre, _Float16* __restrict__ attnh)
{
    const int ch = blockIdx.x, bh = blockIdx.y;
    const int t = threadIdx.x, l = t & 63, w = t >> 6;
    const int r15 = l & 15, kq = l >> 4;

    __shared__ _Float16 Plds[64 * 64];   // swizzled rows of 128 B
    __shared__ float denp[64];
    __shared__ float denf[64];

    const size_t rowbase = (size_t)bh * kN + ch * 64;

    // Phase 1: scores = Q K^T   (A rows = w*16 + r15, K-dim = d = 64)
    f16x8 aq[2], bk[4][2];
    #pragma unroll
    for (int kk = 0; kk < 2; ++kk) {
        aq[kk] = *(const f16x8*)(qh + (rowbase + w * 16 + r15) * 64 + kk * 32 + kq * 8);
        #pragma unroll
        for (int ni = 0; ni < 4; ++ni)
            bk[ni][kk] = *(const f16x8*)(khb + (rowbase + ni * 16 + r15) * 64 + kk * 32 + kq * 8);
    }
    floatx4 sacc[4];
    #pragma unroll
    for (int ni = 0; ni < 4; ++ni) sacc[ni] = (floatx4){0.f, 0.f, 0.f, 0.f};
    #pragma unroll
    for (int kk = 0; kk < 2; ++kk)
        #pragma unroll
        for (int ni = 0; ni < 4; ++ni)
            sacc[ni] = __builtin_amdgcn_mfma_f32_16x16x32_f16(aq[kk], bk[ni][kk], sacc[ni], 0, 0, 0);

    // mask (m <= qn), rowsum, P -> swizzled LDS fp16
    const int qrow = w * 16 + kq * 4;
    float psum[4] = {0.f, 0.f, 0.f, 0.f};
    #pragma unroll
    for (int ni = 0; ni < 4; ++ni) {
        const int m = ni * 16 + r15;
        #pragma unroll
        for (int r = 0; r < 4; ++r) {
            const int row = qrow + r;
            const float v = (m <= row) ? sacc[ni][r] : 0.f;
            psum[r] += v;
            const int byte = row * 128 + ((((unsigned)m >> 3) ^ (row & 7)) << 4) + (m & 7) * 2;
            *(_Float16*)((char*)Plds + byte) = (_Float16)v;
        }
    }
    #pragma unroll
    for (int r = 0; r < 4; ++r) {
        float p = psum[r];
        p += __shfl_xor(p, 1, 16);
        p += __shfl_xor(p, 2, 16);
        p += __shfl_xor(p, 4, 16);
        p += __shfl_xor(p, 8, 16);
        if (r15 == 0) denp[qrow + r] = p;
    }
    __syncthreads();

    // den finalize (64 threads)
    if (t < 64) {
        const _Float16* qp = qh + (rowbase + t) * 64;
        const float* zp = zpre + ((size_t)bh * NCH + ch) * 64;
        float s = denp[t];
        #pragma unroll
        for (int j = 0; j < 8; ++j) {
            f16x8 q8 = *(const f16x8*)(qp + j * 8);
            #pragma unroll
            for (int u = 0; u < 8; ++u) s += (float)q8[u] * zp[j * 8 + u];
        }
        denf[t] = 1.0f / s;
    }

    // Phase 2: O = P V + Q STpre
    f16x8 ap[2], bv[4][2], bs[4][2];
    #pragma unroll
    for (int km = 0; km < 2; ++km)
        ap[km] = *(const f16x8*)((char*)Plds + (w * 16 + r15) * 128 +
                                 (((km * 4 + kq) ^ (r15 & 7)) << 4));
    #pragma unroll
    for (int ni = 0; ni < 4; ++ni) {
        #pragma unroll
        for (int km = 0; km < 2; ++km)
            bv[ni][km] = *(const f16x8*)(vTh + ((size_t)bh * 64 + ni * 16 + r15) * kN +
                                         ch * 64 + km * 32 + kq * 8);
    }
    const _Float16* sp = spre16 + ((size_t)bh * NCH + ch) * CBSTRIDE;
    #pragma unroll
    for (int ni = 0; ni < 4; ++ni)
        #pragma unroll
        for (int kd = 0; kd < 2; ++kd)
            bs[ni][kd] = *(const f16x8*)(sp + (size_t)(ni * 16 + r15) * 64 + kd * 32 + kq * 8);

    floatx4 oacc[4];
    #pragma unroll
    for (int ni = 0; ni < 4; ++ni) oacc[ni] = (floatx4){0.f, 0.f, 0.f, 0.f};
    #pragma unroll
    for (int km = 0; km < 2; ++km)
        #pragma unroll
        for (int ni = 0; ni < 4; ++ni)
            oacc[ni] = __builtin_amdgcn_mfma_f32_16x16x32_f16(ap[km], bv[ni][km], oacc[ni], 0, 0, 0);
    #pragma unroll
    for (int kd = 0; kd < 2; ++kd)
        #pragma unroll
        for (int ni = 0; ni < 4; ++ni)
            oacc[ni] = __builtin_amdgcn_mfma_f32_16x16x32_f16(aq[kd], bs[ni][kd], oacc[ni], 0, 0, 0);
    __syncthreads();   // denf ready

    const int b = bh >> 3, h = bh & 7;
    #pragma unroll
    for (int ni = 0; ni < 4; ++ni) {
        const int e = ni * 16 + r15;
        #pragma unroll
        for (int r = 0; r < 4; ++r) {
            const int qn = qrow + r;
            const float ov = oacc[ni][r] * denf[qn];
            attnh[((size_t)(b * kN + ch * 64 + qn)) * 512 + h * 64 + e] = (_Float16)ov;
        }
    }
}

// ---------------------------------------------------------------------------
// out GEMM: out = attnh @ WoT^T + bo.  BM=BN=128, BK=64, 256 threads.
// A (attnh f16) and B (WoT f16) via global_load_lds, XOR-swizzled.
// ---------------------------------------------------------------------------
__global__ __launch_bounds__(256)
void out_gemm_kernel(const _Float16* __restrict__ A,
                     const _Float16* __restrict__ BT,
                     const float* __restrict__ bo,
                     float* __restrict__ outf)
{
    constexpr int K = 512;
    __shared__ _Float16 As[128 * 64];
    __shared__ _Float16 Bs[128 * 64];

    const int t = threadIdx.x;
    const int l = t & 63;
    const int w = t >> 6;
    const int wm = w >> 1, wn = w & 1;
    const int m0 = blockIdx.y * 128;
    const int n0 = blockIdx.x * 128;

    const int r15 = l & 15, kq = l >> 4, sw = r15 & 7;

    floatx4 acc[4][4];
    #pragma unroll
    for (int mi = 0; mi < 4; ++mi)
        #pragma unroll
        for (int ni = 0; ni < 4; ++ni)
            acc[mi][ni] = (floatx4){0.f, 0.f, 0.f, 0.f};

    const int srow  = t >> 3;
    const int sslot = t & 7;

    const char* Abase = (const char*)(A + (size_t)m0 * K);
    const char* Bbase = (const char*)(BT + (size_t)n0 * K);
    char* AsB = (char*)As;
    char* BsB = (char*)Bs;

    const char* ArdB = (const char*)As + (wm * 64 + r15) * 128;
    const char* BrdB = (const char*)Bs + (wn * 64 + r15) * 128;
    const int sw0 = ((kq ^ sw) << 4);
    const int sw1 = (((4 + kq) ^ sw) << 4);

    for (int k0 = 0; k0 < K; k0 += 64) {
        #pragma unroll
        for (int i = 0; i < 4; ++i) {
            const int row = i * 32 + srow;
            const int gsl = sslot ^ (row & 7);
            async_copy16(AsB + row * 128 + sslot * 16,
                         Abase + (size_t)row * (K * 2) + k0 * 2 + gsl * 16);
            async_copy16(BsB + row * 128 + sslot * 16,
                         Bbase + (size_t)row * (K * 2) + k0 * 2 + gsl * 16);
        }
        __syncthreads();

        f16x8 af[4][2], bf[4][2];
        #pragma unroll
        for (int i = 0; i < 4; ++i) {
            af[i][0] = *(const f16x8*)(ArdB + i * 2048 + sw0);
            af[i][1] = *(const f16x8*)(ArdB + i * 2048 + sw1);
            bf[i][0] = *(const f16x8*)(BrdB + i * 2048 + sw0);
            bf[i][1] = *(const f16x8*)(BrdB + i * 2048 + sw1);
        }
        #pragma unroll
        for (int kk = 0; kk < 2; ++kk)
            #pragma unroll
            for (int mi = 0; mi < 4; ++mi)
                #pragma unroll
                for (int ni = 0; ni < 4; ++ni)
                    acc[mi][ni] = __builtin_amdgcn_mfma_f32_16x16x32_f16(
                        af[mi][kk], bf[ni][kk], acc[mi][ni], 0, 0, 0);
        __syncthreads();
    }

    #pragma unroll
    for (int ni = 0; ni < 4; ++ni) {
        const int col = n0 + wn * 64 + ni * 16 + r15;
        const float bias = bo[col];
        #pragma unroll
        for (int mi = 0; mi < 4; ++mi) {
            const int row = m0 + wm * 64 + mi * 16 + kq * 4;
            #pragma unroll
            for (int r = 0; r < 4; ++r)
                outf[(size_t)(row + r) * 512 + col] = acc[mi][ni][r] + bias;
        }
    }
}

// ---------------------------------------------------------------------------
extern "C" void kernel_launch(void* const* d_in, const int* in_sizes, int n_in,
                              void* d_out, int out_size, void* d_ws, size_t ws_size,
                              hipStream_t stream)
{
    const float* x  = (const float*)d_in[0];
    const float* Wq = (const float*)d_in[1];
    const float* Wk = (const float*)d_in[2];
    const float* Wv = (const float*)d_in[3];
    const float* Wo = (const float*)d_in[4];
    const float* bo = (const float*)d_in[5];
    float* out = (float*)d_out;

    char* ws = (char*)d_ws;
    _Float16* qh     = (_Float16*)(ws + 0);          // 4,194,304 B [bh][n][64]
    _Float16* khb    = (_Float16*)(ws + 4194304);    // 4,194,304 B [bh][n][64]
    _Float16* kTh    = (_Float16*)(ws + 8388608);    // 4,194,304 B [bh][64][n]
    _Float16* vTh    = (_Float16*)(ws + 12582912);   // 4,194,304 B [bh][64][n]
    _Float16* spre16 = (_Float16*)(ws + 16777216);   // 4,259,840 B [bh][ch][4160] f16
    float*    zpre   = (float*)(ws + 21037056);      //   131,072 B [bh][ch][64] f32
    _Float16* WT     = (_Float16*)(ws + 21168128);   // 1,572,864 B [1536][512] f16
    _Float16* WoT    = (_Float16*)(ws + 22740992);   //   524,288 B [512][512] f16
    _Float16* attnh  = (_Float16*)(ws + 23265280);   // 4,194,304 B [4096][512] f16
    _Float16* xh     = (_Float16*)(ws + 27459584);   // 4,194,304 B [4096][512] f16

    prep_kernel<<<dim3(16, 16, 12), 256, 0, stream>>>(Wq, Wk, Wv, Wo, x, WT, WoT, xh);
    qkv_gemm_kernel<<<dim3(6, NROWS / 128), 512, 0, stream>>>(
        xh, WT, qh, khb, kTh, vTh);
    scan_kernel<<<dim3(2, kBH), 256, 0, stream>>>(kTh, vTh, spre16, zpre);
    chunk_out_kernel<<<dim3(NCH, kBH), 256, 0, stream>>>(
        qh, khb, vTh, spre16, zpre, attnh);
    out_gemm_kernel<<<dim3(4, NROWS / 128), 256, 0, stream>>>(
        attnh, WoT, bo, out);
}

// Round 9
// 66.529 us; speedup vs baseline: 1.1019x; 1.1019x over previous
//
#include <hip/hip_runtime.h>

// Problem constants (reference: B=2, N=2048, DIM=512, H=8, DH=64)
constexpr int kB   = 2;
constexpr int kN   = 2048;
constexpr int kDIM = 512;
constexpr int kH   = 8;
constexpr int kDH  = 64;
constexpr int kBH  = kB * kH;          // 16
constexpr int NROWS = kB * kN;         // 4096
constexpr int CHUNK = 64;
constexpr int NCH   = kN / CHUNK;      // 32
constexpr float kEPS = 1e-3f;

typedef _Float16 f16x8 __attribute__((ext_vector_type(8)));
typedef _Float16 f16x4 __attribute__((ext_vector_type(4)));
typedef float    floatx4 __attribute__((ext_vector_type(4)));

__device__ __forceinline__ void async_copy16(void* lds, const void* g) {
    __builtin_amdgcn_global_load_lds(
        (const __attribute__((address_space(1))) void*)g,
        (__attribute__((address_space(3))) void*)lds,
        16, 0, 0);
}

// ---------------------------------------------------------------------------
// Prep: z=0..3 -> weight transpose+convert (Wq,Wk,Wv -> WT[1536][512], Wo -> WoT);
//       z=4..11 -> x fp32 -> fp16 straight convert.
// grid (16,16,12), block 256.
// ---------------------------------------------------------------------------
__global__ __launch_bounds__(256)
void prep_kernel(const float* __restrict__ Wq, const float* __restrict__ Wk,
                 const float* __restrict__ Wv, const float* __restrict__ Wo,
                 const float* __restrict__ x,
                 _Float16* __restrict__ WT, _Float16* __restrict__ WoT,
                 _Float16* __restrict__ xh)
{
    const int z = blockIdx.z;
    if (z >= 4) {
        const size_t base = (((size_t)(z - 4) * 256 + blockIdx.y * 16 + blockIdx.x) * 256 +
                             threadIdx.x) * 4;
        const float4 a = *(const float4*)(x + base);
        f16x4 o;
        o[0] = (_Float16)a.x; o[1] = (_Float16)a.y;
        o[2] = (_Float16)a.z; o[3] = (_Float16)a.w;
        *(f16x4*)(xh + base) = o;
        return;
    }
    __shared__ float tile[32][33];
    const float* src = (z == 0) ? Wq : (z == 1) ? Wk : (z == 2) ? Wv : Wo;
    _Float16* dst = (z < 3) ? (WT + (size_t)z * 512 * 512) : WoT;
    const int r0 = blockIdx.y * 32, c0 = blockIdx.x * 32;
    const int tr = threadIdx.x >> 5, tc = threadIdx.x & 31;
    #pragma unroll
    for (int i = 0; i < 4; ++i)
        tile[tr + 8 * i][tc] = src[(size_t)(r0 + tr + 8 * i) * 512 + c0 + tc];
    __syncthreads();
    #pragma unroll
    for (int i = 0; i < 4; ++i)
        dst[(size_t)(c0 + tr + 8 * i) * 512 + r0 + tc] = (_Float16)tile[tc][tr + 8 * i];
}

// ---------------------------------------------------------------------------
// qkv MFMA GEMM.  BM=128, BN=256, BK=64, 512 threads (8 waves, 2m x 4n).
// A (xh f16) and B (WT f16) via global_load_lds, XOR-swizzled source+read.
// Epilogue -> fp16 qh,khb row-major [bh][n][64] (relu+eps on q,k),
//             fp16 kTh,vTh transposed [bh][d][n].  grid (6, 32).
// ---------------------------------------------------------------------------
__global__ __launch_bounds__(512)
void qkv_gemm_kernel(const _Float16* __restrict__ A,
                     const _Float16* __restrict__ BT,
                     _Float16* __restrict__ qh,
                     _Float16* __restrict__ khb,
                     _Float16* __restrict__ kTh,
                     _Float16* __restrict__ vTh)
{
    constexpr int K = 512;
    __shared__ _Float16 As[128 * 64];   // 16 KB, rows of 128 B, swizzled
    __shared__ _Float16 Bs[256 * 64];   // 32 KB

    const int t = threadIdx.x;
    const int l = t & 63;
    const int w = t >> 6;               // 0..7
    const int wm = w >> 2, wn = w & 3;  // 2 x 4 wave grid
    const int m0 = blockIdx.y * 128;
    const int n0 = blockIdx.x * 256;

    const int r15 = l & 15, kq = l >> 4, sw = r15 & 7;

    floatx4 acc[4][4];
    #pragma unroll
    for (int mi = 0; mi < 4; ++mi)
        #pragma unroll
        for (int ni = 0; ni < 4; ++ni)
            acc[mi][ni] = (floatx4){0.f, 0.f, 0.f, 0.f};

    const char* Abase = (const char*)(A + (size_t)m0 * K);
    const char* Bbase = (const char*)(BT + (size_t)n0 * K);
    char* AsB = (char*)As;
    char* BsB = (char*)Bs;

    const char* ArdB = (const char*)As + (wm * 64 + r15) * 128;
    const char* BrdB = (const char*)Bs + (wn * 64 + r15) * 128;
    const int sw0 = ((kq ^ sw) << 4);
    const int sw1 = (((4 + kq) ^ sw) << 4);

    for (int k0 = 0; k0 < K; k0 += 64) {
        #pragma unroll
        for (int i = 0; i < 2; ++i) {
            const int s = i * 512 + t;
            const int row = s >> 3, sl = s & 7;
            const int gsl = sl ^ (row & 7);
            async_copy16(AsB + row * 128 + sl * 16,
                         Abase + (size_t)row * (K * 2) + k0 * 2 + gsl * 16);
        }
        #pragma unroll
        for (int i = 0; i < 4; ++i) {
            const int s = i * 512 + t;
            const int row = s >> 3, sl = s & 7;
            const int gsl = sl ^ (row & 7);
            async_copy16(BsB + row * 128 + sl * 16,
                         Bbase + (size_t)row * (K * 2) + k0 * 2 + gsl * 16);
        }
        __syncthreads();

        f16x8 af[4][2], bf[4][2];
        #pragma unroll
        for (int i = 0; i < 4; ++i) {
            af[i][0] = *(const f16x8*)(ArdB + i * 2048 + sw0);
            af[i][1] = *(const f16x8*)(ArdB + i * 2048 + sw1);
            bf[i][0] = *(const f16x8*)(BrdB + i * 2048 + sw0);
            bf[i][1] = *(const f16x8*)(BrdB + i * 2048 + sw1);
        }
        #pragma unroll
        for (int kk = 0; kk < 2; ++kk)
            #pragma unroll
            for (int mi = 0; mi < 4; ++mi)
                #pragma unroll
                for (int ni = 0; ni < 4; ++ni)
                    acc[mi][ni] = __builtin_amdgcn_mfma_f32_16x16x32_f16(
                        af[mi][kk], bf[ni][kk], acc[mi][ni], 0, 0, 0);
        __syncthreads();
    }

    #pragma unroll
    for (int ni = 0; ni < 4; ++ni) {
        const int col = n0 + wn * 64 + ni * 16 + r15;   // 0..1535
        const int which = col >> 9;
        const int h = (col >> 6) & 7, e = col & 63;
        #pragma unroll
        for (int mi = 0; mi < 4; ++mi) {
            const int row0 = m0 + wm * 64 + mi * 16 + kq * 4;
            const int b = row0 >> 11, nn = row0 & 2047;
            const int bh = b * 8 + h;
            float vv[4];
            #pragma unroll
            for (int r = 0; r < 4; ++r) {
                float v = acc[mi][ni][r];
                if (which < 2) v = fmaxf(v, 0.f) + kEPS;
                vv[r] = v;
            }
            if (which == 0) {
                #pragma unroll
                for (int r = 0; r < 4; ++r)
                    qh[((size_t)bh * kN + nn + r) * 64 + e] = (_Float16)vv[r];
            } else if (which == 1) {
                #pragma unroll
                for (int r = 0; r < 4; ++r)
                    khb[((size_t)bh * kN + nn + r) * 64 + e] = (_Float16)vv[r];
                f16x4 t4;
                t4[0] = (_Float16)vv[0]; t4[1] = (_Float16)vv[1];
                t4[2] = (_Float16)vv[2]; t4[3] = (_Float16)vv[3];
                *(f16x4*)(kTh + ((size_t)bh * 64 + e) * kN + nn) = t4;
            } else {
                f16x4 t4;
                t4[0] = (_Float16)vv[0]; t4[1] = (_Float16)vv[1];
                t4[2] = (_Float16)vv[2]; t4[3] = (_Float16)vv[3];
                *(f16x4*)(vTh + ((size_t)bh * 64 + e) * kN + nn) = t4;
            }
        }
    }
}

// ---------------------------------------------------------------------------
// chunk_sum (MFMA): S_c[e][d] = sum_n v[n][e] k[n][d], written fp16 [e][d];
// z_c[d] = sum_n k[n][d], fp32.  grid (NCH, BH), block 256.
// ---------------------------------------------------------------------------
__global__ __launch_bounds__(256)
void chunk_sum_kernel(const _Float16* __restrict__ kTh, const _Float16* __restrict__ vTh,
                      _Float16* __restrict__ csum16, float* __restrict__ zsum)
{
    const int ch = blockIdx.x, bh = blockIdx.y;
    const int t = threadIdx.x, l = t & 63, w = t >> 6;
    const int r15 = l & 15, kq = l >> 4;

    const _Float16* vbase = vTh + (size_t)bh * 64 * kN + ch * 64;
    const _Float16* kbase = kTh + (size_t)bh * 64 * kN + ch * 64;

    f16x8 av[2], bk[4][2];
    #pragma unroll
    for (int kk = 0; kk < 2; ++kk) {
        av[kk] = *(const f16x8*)(vbase + (size_t)(w * 16 + r15) * kN + kk * 32 + kq * 8);
        #pragma unroll
        for (int ni = 0; ni < 4; ++ni)
            bk[ni][kk] = *(const f16x8*)(kbase + (size_t)(ni * 16 + r15) * kN + kk * 32 + kq * 8);
    }
    floatx4 acc[4];
    #pragma unroll
    for (int ni = 0; ni < 4; ++ni) acc[ni] = (floatx4){0.f, 0.f, 0.f, 0.f};
    #pragma unroll
    for (int kk = 0; kk < 2; ++kk)
        #pragma unroll
        for (int ni = 0; ni < 4; ++ni)
            acc[ni] = __builtin_amdgcn_mfma_f32_16x16x32_f16(av[kk], bk[ni][kk], acc[ni], 0, 0, 0);

    _Float16* out = csum16 + ((size_t)bh * NCH + ch) * 4096;
    #pragma unroll
    for (int ni = 0; ni < 4; ++ni)
        #pragma unroll
        for (int r = 0; r < 4; ++r)
            out[(size_t)(w * 16 + kq * 4 + r) * 64 + ni * 16 + r15] = (_Float16)acc[ni][r];

    if (t < 64) {
        const _Float16* kp = kbase + (size_t)t * kN;
        float z = 0.f;
        #pragma unroll
        for (int j = 0; j < 8; ++j) {
            f16x8 v8 = *(const f16x8*)(kp + j * 8);
            #pragma unroll
            for (int u = 0; u < 8; ++u) z += (float)v8[u];
        }
        zsum[((size_t)bh * NCH + ch) * 64 + t] = z;
    }
}

// ---------------------------------------------------------------------------
// chunk_out (MFMA): phase 0 sums chunk-sums c<ch into swizzled LDS Spre (f16)
// and z into LDS (f32); then scores = QK^T (masked) -> P fp16 swizzled LDS,
// O = P V + Q Spre, den = rowsum(P) + q.z_pre, attn = O/den (fp16).
// grid (NCH, BH), block 256 (wave w = query rows w*16..w*16+15).
// ---------------------------------------------------------------------------
__global__ __launch_bounds__(256)
void chunk_out_kernel(const _Float16* __restrict__ qh, const _Float16* __restrict__ khb,
                      const _Float16* __restrict__ vTh, const _Float16* __restrict__ csum16,
                      const float* __restrict__ zsum, _Float16* __restrict__ attnh)
{
    const int ch = blockIdx.x, bh = blockIdx.y;
    const int t = threadIdx.x, l = t & 63, w = t >> 6;
    const int r15 = l & 15, kq = l >> 4;

    __shared__ _Float16 Plds[64 * 64];   // swizzled rows of 128 B
    __shared__ _Float16 Spre[64 * 64];   // swizzled rows of 128 B (S_pre [e][d])
    __shared__ float zprel[64];
    __shared__ float denp[64];
    __shared__ float denf[64];

    // ---- Phase 0: exclusive prefix for this chunk (block-local sum of c < ch)
    {
        const int e0 = t >> 2;          // 0..63
        const int sg = (t & 3) * 2;     // slot pair sg, sg+1 (16B each)
        float a0[8] = {}, a1[8] = {};
        const _Float16* cbase = csum16 + (size_t)bh * NCH * 4096 + e0 * 64 + sg * 8;
        for (int c = 0; c < ch; ++c) {
            const _Float16* cp = cbase + (size_t)c * 4096;
            const f16x8 u0 = *(const f16x8*)(cp);
            const f16x8 u1 = *(const f16x8*)(cp + 8);
            #pragma unroll
            for (int j = 0; j < 8; ++j) { a0[j] += (float)u0[j]; a1[j] += (float)u1[j]; }
        }
        f16x8 s0, s1;
        #pragma unroll
        for (int j = 0; j < 8; ++j) { s0[j] = (_Float16)a0[j]; s1[j] = (_Float16)a1[j]; }
        char* SB = (char*)Spre;
        *(f16x8*)(SB + e0 * 128 + ((sg ^ (e0 & 7)) << 4)) = s0;
        *(f16x8*)(SB + e0 * 128 + (((sg + 1) ^ (e0 & 7)) << 4)) = s1;
        if (t < 64) {
            float z = 0.f;
            for (int c = 0; c < ch; ++c)
                z += zsum[((size_t)bh * NCH + c) * 64 + t];
            zprel[t] = z;
        }
    }

    const size_t rowbase = (size_t)bh * kN + ch * 64;

    // Phase 1: scores = Q K^T   (A rows = w*16 + r15, K-dim = d = 64)
    f16x8 aq[2], bk[4][2];
    #pragma unroll
    for (int kk = 0; kk < 2; ++kk) {
        aq[kk] = *(const f16x8*)(qh + (rowbase + w * 16 + r15) * 64 + kk * 32 + kq * 8);
        #pragma unroll
        for (int ni = 0; ni < 4; ++ni)
            bk[ni][kk] = *(const f16x8*)(khb + (rowbase + ni * 16 + r15) * 64 + kk * 32 + kq * 8);
    }
    floatx4 sacc[4];
    #pragma unroll
    for (int ni = 0; ni < 4; ++ni) sacc[ni] = (floatx4){0.f, 0.f, 0.f, 0.f};
    #pragma unroll
    for (int kk = 0; kk < 2; ++kk)
        #pragma unroll
        for (int ni = 0; ni < 4; ++ni)
            sacc[ni] = __builtin_amdgcn_mfma_f32_16x16x32_f16(aq[kk], bk[ni][kk], sacc[ni], 0, 0, 0);

    // mask (m <= qn), rowsum, P -> swizzled LDS fp16
    const int qrow = w * 16 + kq * 4;
    float psum[4] = {0.f, 0.f, 0.f, 0.f};
    #pragma unroll
    for (int ni = 0; ni < 4; ++ni) {
        const int m = ni * 16 + r15;
        #pragma unroll
        for (int r = 0; r < 4; ++r) {
            const int row = qrow + r;
            const float v = (m <= row) ? sacc[ni][r] : 0.f;
            psum[r] += v;
            const int byte = row * 128 + ((((unsigned)m >> 3) ^ (row & 7)) << 4) + (m & 7) * 2;
            *(_Float16*)((char*)Plds + byte) = (_Float16)v;
        }
    }
    #pragma unroll
    for (int r = 0; r < 4; ++r) {
        float p = psum[r];
        p += __shfl_xor(p, 1, 16);
        p += __shfl_xor(p, 2, 16);
        p += __shfl_xor(p, 4, 16);
        p += __shfl_xor(p, 8, 16);
        if (r15 == 0) denp[qrow + r] = p;
    }
    __syncthreads();   // Spre, zprel, denp all visible

    // den finalize (64 threads)
    if (t < 64) {
        const _Float16* qp = qh + (rowbase + t) * 64;
        float s = denp[t];
        #pragma unroll
        for (int j = 0; j < 8; ++j) {
            f16x8 q8 = *(const f16x8*)(qp + j * 8);
            #pragma unroll
            for (int u = 0; u < 8; ++u) s += (float)q8[u] * zprel[j * 8 + u];
        }
        denf[t] = 1.0f / s;
    }

    // Phase 2: O = P V + Q Spre
    f16x8 ap[2], bv[4][2], bs[4][2];
    #pragma unroll
    for (int km = 0; km < 2; ++km)
        ap[km] = *(const f16x8*)((char*)Plds + (w * 16 + r15) * 128 +
                                 (((km * 4 + kq) ^ (r15 & 7)) << 4));
    #pragma unroll
    for (int ni = 0; ni < 4; ++ni) {
        #pragma unroll
        for (int km = 0; km < 2; ++km)
            bv[ni][km] = *(const f16x8*)(vTh + ((size_t)bh * 64 + ni * 16 + r15) * kN +
                                         ch * 64 + km * 32 + kq * 8);
    }
    #pragma unroll
    for (int ni = 0; ni < 4; ++ni) {
        const int e = ni * 16 + r15;
        #pragma unroll
        for (int kd = 0; kd < 2; ++kd)
            bs[ni][kd] = *(const f16x8*)((char*)Spre + e * 128 +
                                         (((kd * 4 + kq) ^ (e & 7)) << 4));
    }

    floatx4 oacc[4];
    #pragma unroll
    for (int ni = 0; ni < 4; ++ni) oacc[ni] = (floatx4){0.f, 0.f, 0.f, 0.f};
    #pragma unroll
    for (int km = 0; km < 2; ++km)
        #pragma unroll
        for (int ni = 0; ni < 4; ++ni)
            oacc[ni] = __builtin_amdgcn_mfma_f32_16x16x32_f16(ap[km], bv[ni][km], oacc[ni], 0, 0, 0);
    #pragma unroll
    for (int kd = 0; kd < 2; ++kd)
        #pragma unroll
        for (int ni = 0; ni < 4; ++ni)
            oacc[ni] = __builtin_amdgcn_mfma_f32_16x16x32_f16(aq[kd], bs[ni][kd], oacc[ni], 0, 0, 0);
    __syncthreads();   // denf ready

    const int b = bh >> 3, h = bh & 7;
    #pragma unroll
    for (int ni = 0; ni < 4; ++ni) {
        const int e = ni * 16 + r15;
        #pragma unroll
        for (int r = 0; r < 4; ++r) {
            const int qn = qrow + r;
            const float ov = oacc[ni][r] * denf[qn];
            attnh[((size_t)(b * kN + ch * 64 + qn)) * 512 + h * 64 + e] = (_Float16)ov;
        }
    }
}

// ---------------------------------------------------------------------------
// out GEMM: out = attnh @ WoT^T + bo.  BM=BN=128, BK=64, 256 threads.
// ---------------------------------------------------------------------------
__global__ __launch_bounds__(256)
void out_gemm_kernel(const _Float16* __restrict__ A,
                     const _Float16* __restrict__ BT,
                     const float* __restrict__ bo,
                     float* __restrict__ outf)
{
    constexpr int K = 512;
    __shared__ _Float16 As[128 * 64];
    __shared__ _Float16 Bs[128 * 64];

    const int t = threadIdx.x;
    const int l = t & 63;
    const int w = t >> 6;
    const int wm = w >> 1, wn = w & 1;
    const int m0 = blockIdx.y * 128;
    const int n0 = blockIdx.x * 128;

    const int r15 = l & 15, kq = l >> 4, sw = r15 & 7;

    floatx4 acc[4][4];
    #pragma unroll
    for (int mi = 0; mi < 4; ++mi)
        #pragma unroll
        for (int ni = 0; ni < 4; ++ni)
            acc[mi][ni] = (floatx4){0.f, 0.f, 0.f, 0.f};

    const int srow  = t >> 3;
    const int sslot = t & 7;

    const char* Abase = (const char*)(A + (size_t)m0 * K);
    const char* Bbase = (const char*)(BT + (size_t)n0 * K);
    char* AsB = (char*)As;
    char* BsB = (char*)Bs;

    const char* ArdB = (const char*)As + (wm * 64 + r15) * 128;
    const char* BrdB = (const char*)Bs + (wn * 64 + r15) * 128;
    const int sw0 = ((kq ^ sw) << 4);
    const int sw1 = (((4 + kq) ^ sw) << 4);

    for (int k0 = 0; k0 < K; k0 += 64) {
        #pragma unroll
        for (int i = 0; i < 4; ++i) {
            const int row = i * 32 + srow;
            const int gsl = sslot ^ (row & 7);
            async_copy16(AsB + row * 128 + sslot * 16,
                         Abase + (size_t)row * (K * 2) + k0 * 2 + gsl * 16);
            async_copy16(BsB + row * 128 + sslot * 16,
                         Bbase + (size_t)row * (K * 2) + k0 * 2 + gsl * 16);
        }
        __syncthreads();

        f16x8 af[4][2], bf[4][2];
        #pragma unroll
        for (int i = 0; i < 4; ++i) {
            af[i][0] = *(const f16x8*)(ArdB + i * 2048 + sw0);
            af[i][1] = *(const f16x8*)(ArdB + i * 2048 + sw1);
            bf[i][0] = *(const f16x8*)(BrdB + i * 2048 + sw0);
            bf[i][1] = *(const f16x8*)(BrdB + i * 2048 + sw1);
        }
        #pragma unroll
        for (int kk = 0; kk < 2; ++kk)
            #pragma unroll
            for (int mi = 0; mi < 4; ++mi)
                #pragma unroll
                for (int ni = 0; ni < 4; ++ni)
                    acc[mi][ni] = __builtin_amdgcn_mfma_f32_16x16x32_f16(
                        af[mi][kk], bf[ni][kk], acc[mi][ni], 0, 0, 0);
        __syncthreads();
    }

    #pragma unroll
    for (int ni = 0; ni < 4; ++ni) {
        const int col = n0 + wn * 64 + ni * 16 + r15;
        const float bias = bo[col];
        #pragma unroll
        for (int mi = 0; mi < 4; ++mi) {
            const int row = m0 + wm * 64 + mi * 16 + kq * 4;
            #pragma unroll
            for (int r = 0; r < 4; ++r)
                outf[(size_t)(row + r) * 512 + col] = acc[mi][ni][r] + bias;
        }
    }
}

// ---------------------------------------------------------------------------
extern "C" void kernel_launch(void* const* d_in, const int* in_sizes, int n_in,
                              void* d_out, int out_size, void* d_ws, size_t ws_size,
                              hipStream_t stream)
{
    const float* x  = (const float*)d_in[0];
    const float* Wq = (const float*)d_in[1];
    const float* Wk = (const float*)d_in[2];
    const float* Wv = (const float*)d_in[3];
    const float* Wo = (const float*)d_in[4];
    const float* bo = (const float*)d_in[5];
    float* out = (float*)d_out;

    char* ws = (char*)d_ws;
    _Float16* qh     = (_Float16*)(ws + 0);          // 4,194,304 B [bh][n][64]
    _Float16* khb    = (_Float16*)(ws + 4194304);    // 4,194,304 B [bh][n][64]
    _Float16* kTh    = (_Float16*)(ws + 8388608);    // 4,194,304 B [bh][64][n]
    _Float16* vTh    = (_Float16*)(ws + 12582912);   // 4,194,304 B [bh][64][n]
    _Float16* csum16 = (_Float16*)(ws + 16777216);   // 4,194,304 B [bh][ch][4096] f16
    float*    zsum   = (float*)(ws + 20971520);      //   131,072 B [bh][ch][64] f32
    _Float16* WT     = (_Float16*)(ws + 21102592);   // 1,572,864 B [1536][512] f16
    _Float16* WoT    = (_Float16*)(ws + 22675456);   //   524,288 B [512][512] f16
    _Float16* attnh  = (_Float16*)(ws + 23199744);   // 4,194,304 B [4096][512] f16
    _Float16* xh     = (_Float16*)(ws + 27394048);   // 4,194,304 B [4096][512] f16

    prep_kernel<<<dim3(16, 16, 12), 256, 0, stream>>>(Wq, Wk, Wv, Wo, x, WT, WoT, xh);
    qkv_gemm_kernel<<<dim3(6, NROWS / 128), 512, 0, stream>>>(
        xh, WT, qh, khb, kTh, vTh);
    chunk_sum_kernel<<<dim3(NCH, kBH), 256, 0, stream>>>(kTh, vTh, csum16, zsum);
    chunk_out_kernel<<<dim3(NCH, kBH), 256, 0, stream>>>(
        qh, khb, vTh, csum16, zsum, attnh);
    out_gemm_kernel<<<dim3(4, NROWS / 128), 256, 0, stream>>>(
        attnh, WoT, bo, out);
}

// Round 10
// 56.580 us; speedup vs baseline: 1.2957x; 1.1758x over previous
//
#include <hip/hip_runtime.h>

// Problem constants (reference: B=2, N=2048, DIM=512, H=8, DH=64)
constexpr int kB   = 2;
constexpr int kN   = 2048;
constexpr int kDIM = 512;
constexpr int kH   = 8;
constexpr int kDH  = 64;
constexpr int kBH  = kB * kH;          // 16
constexpr int NROWS = kB * kN;         // 4096
constexpr int CHUNK = 64;
constexpr int NCH   = kN / CHUNK;      // 32
constexpr int CBSTRIDE = kDH * kDH + kDH;  // 4160 per (bh,chunk): ST[e][d] (4096) + z (64)
constexpr float kEPS = 1e-3f;

typedef _Float16 f16x8 __attribute__((ext_vector_type(8)));
typedef _Float16 f16x4 __attribute__((ext_vector_type(4)));
typedef float    floatx4 __attribute__((ext_vector_type(4)));

__device__ __forceinline__ void async_copy16(void* lds, const void* g) {
    __builtin_amdgcn_global_load_lds(
        (const __attribute__((address_space(1))) void*)g,
        (__attribute__((address_space(3))) void*)lds,
        16, 0, 0);
}

// ---------------------------------------------------------------------------
// Prep: z=0..3 -> weight transpose+convert (Wq,Wk,Wv -> WT[1536][512], Wo -> WoT);
//       z=4..11 -> x fp32 -> fp16 straight convert.
// grid (16,16,12), block 256.
// ---------------------------------------------------------------------------
__global__ __launch_bounds__(256)
void prep_kernel(const float* __restrict__ Wq, const float* __restrict__ Wk,
                 const float* __restrict__ Wv, const float* __restrict__ Wo,
                 const float* __restrict__ x,
                 _Float16* __restrict__ WT, _Float16* __restrict__ WoT,
                 _Float16* __restrict__ xh)
{
    const int z = blockIdx.z;
    if (z >= 4) {
        const size_t base = (((size_t)(z - 4) * 256 + blockIdx.y * 16 + blockIdx.x) * 256 +
                             threadIdx.x) * 4;
        const float4 a = *(const float4*)(x + base);
        f16x4 o;
        o[0] = (_Float16)a.x; o[1] = (_Float16)a.y;
        o[2] = (_Float16)a.z; o[3] = (_Float16)a.w;
        *(f16x4*)(xh + base) = o;
        return;
    }
    __shared__ float tile[32][33];
    const float* src = (z == 0) ? Wq : (z == 1) ? Wk : (z == 2) ? Wv : Wo;
    _Float16* dst = (z < 3) ? (WT + (size_t)z * 512 * 512) : WoT;
    const int r0 = blockIdx.y * 32, c0 = blockIdx.x * 32;
    const int tr = threadIdx.x >> 5, tc = threadIdx.x & 31;
    #pragma unroll
    for (int i = 0; i < 4; ++i)
        tile[tr + 8 * i][tc] = src[(size_t)(r0 + tr + 8 * i) * 512 + c0 + tc];
    __syncthreads();
    #pragma unroll
    for (int i = 0; i < 4; ++i)
        dst[(size_t)(c0 + tr + 8 * i) * 512 + r0 + tc] = (_Float16)tile[tc][tr + 8 * i];
}

// ---------------------------------------------------------------------------
// qkv MFMA GEMM.  BM=BN=128, BK=64, 256 threads (4 waves, 2x2).
// A (xh f16) and B (WT f16) via global_load_lds, XOR-swizzled source+read.
// 1-D grid of 384 blocks, bijective XCD swizzle; bx = col-tile (B-panel)
// decomposed so same-panel blocks cluster per XCD.
// Epilogue -> fp16 qh,khb row-major [bh][n][64] (relu+eps on q,k),
//             fp16 kTh,vTh transposed [bh][d][n].
// ---------------------------------------------------------------------------
__global__ __launch_bounds__(256)
void qkv_gemm_kernel(const _Float16* __restrict__ A,
                     const _Float16* __restrict__ BT,
                     _Float16* __restrict__ qh,
                     _Float16* __restrict__ khb,
                     _Float16* __restrict__ kTh,
                     _Float16* __restrict__ vTh)
{
    constexpr int K = 512;
    __shared__ _Float16 As[128 * 64];   // 16 KB, rows of 128 B, swizzled
    __shared__ _Float16 Bs[128 * 64];   // 16 KB

    // XCD-bijective swizzle: 384 blocks, 8 XCDs, 48 per XCD (384 % 8 == 0).
    const int bid = blockIdx.x;
    const int swz = (bid & 7) * 48 + (bid >> 3);
    const int bx = swz >> 5;            // 0..11 col-tile (B-panel)
    const int by = swz & 31;            // 0..31 row-tile

    const int t = threadIdx.x;
    const int l = t & 63;
    const int w = t >> 6;
    const int wm = w >> 1, wn = w & 1;
    const int m0 = by * 128;
    const int n0 = bx * 128;

    const int r15 = l & 15, kq = l >> 4, sw = r15 & 7;

    floatx4 acc[4][4];
    #pragma unroll
    for (int mi = 0; mi < 4; ++mi)
        #pragma unroll
        for (int ni = 0; ni < 4; ++ni)
            acc[mi][ni] = (floatx4){0.f, 0.f, 0.f, 0.f};

    const int srow  = t >> 3;       // 0..31
    const int sslot = t & 7;        // 16B slot within 128B row

    const char* Abase = (const char*)(A + (size_t)m0 * K);
    const char* Bbase = (const char*)(BT + (size_t)n0 * K);
    char* AsB = (char*)As;
    char* BsB = (char*)Bs;

    const char* ArdB = (const char*)As + (wm * 64 + r15) * 128;
    const char* BrdB = (const char*)Bs + (wn * 64 + r15) * 128;
    const int sw0 = ((kq ^ sw) << 4);
    const int sw1 = (((4 + kq) ^ sw) << 4);

    for (int k0 = 0; k0 < K; k0 += 64) {
        #pragma unroll
        for (int i = 0; i < 4; ++i) {
            const int row = i * 32 + srow;
            const int gsl = sslot ^ (row & 7);
            async_copy16(AsB + row * 128 + sslot * 16,
                         Abase + (size_t)row * (K * 2) + k0 * 2 + gsl * 16);
            async_copy16(BsB + row * 128 + sslot * 16,
                         Bbase + (size_t)row * (K * 2) + k0 * 2 + gsl * 16);
        }
        __syncthreads();

        f16x8 af[4][2], bf[4][2];
        #pragma unroll
        for (int i = 0; i < 4; ++i) {
            af[i][0] = *(const f16x8*)(ArdB + i * 2048 + sw0);
            af[i][1] = *(const f16x8*)(ArdB + i * 2048 + sw1);
            bf[i][0] = *(const f16x8*)(BrdB + i * 2048 + sw0);
            bf[i][1] = *(const f16x8*)(BrdB + i * 2048 + sw1);
        }
        #pragma unroll
        for (int kk = 0; kk < 2; ++kk)
            #pragma unroll
            for (int mi = 0; mi < 4; ++mi)
                #pragma unroll
                for (int ni = 0; ni < 4; ++ni)
                    acc[mi][ni] = __builtin_amdgcn_mfma_f32_16x16x32_f16(
                        af[mi][kk], bf[ni][kk], acc[mi][ni], 0, 0, 0);
        __syncthreads();
    }

    // Epilogue.  C fragment: row = kq*4 + r, col = r15 (within each 16x16).
    #pragma unroll
    for (int ni = 0; ni < 4; ++ni) {
        const int col = n0 + wn * 64 + ni * 16 + r15;   // 0..1535
        const int which = col >> 9;
        const int h = (col >> 6) & 7, e = col & 63;
        #pragma unroll
        for (int mi = 0; mi < 4; ++mi) {
            const int row0 = m0 + wm * 64 + mi * 16 + kq * 4;
            const int b = row0 >> 11, nn = row0 & 2047;
            const int bh = b * 8 + h;
            float vv[4];
            #pragma unroll
            for (int r = 0; r < 4; ++r) {
                float v = acc[mi][ni][r];
                if (which < 2) v = fmaxf(v, 0.f) + kEPS;
                vv[r] = v;
            }
            if (which == 0) {
                #pragma unroll
                for (int r = 0; r < 4; ++r)
                    qh[((size_t)bh * kN + nn + r) * 64 + e] = (_Float16)vv[r];
            } else if (which == 1) {
                #pragma unroll
                for (int r = 0; r < 4; ++r)
                    khb[((size_t)bh * kN + nn + r) * 64 + e] = (_Float16)vv[r];
                f16x4 t4;
                t4[0] = (_Float16)vv[0]; t4[1] = (_Float16)vv[1];
                t4[2] = (_Float16)vv[2]; t4[3] = (_Float16)vv[3];
                *(f16x4*)(kTh + ((size_t)bh * 64 + e) * kN + nn) = t4;
            } else {
                f16x4 t4;
                t4[0] = (_Float16)vv[0]; t4[1] = (_Float16)vv[1];
                t4[2] = (_Float16)vv[2]; t4[3] = (_Float16)vv[3];
                *(f16x4*)(vTh + ((size_t)bh * 64 + e) * kN + nn) = t4;
            }
        }
    }
}

// ---------------------------------------------------------------------------
// chunk_sum (MFMA): ST_c[e][d] = sum_n v[n][e] k[n][d]  (A=vT, B=kT, K-dim=n)
// z_c[d] = sum_n k[n][d].  grid (NCH, BH), block 256.
// ---------------------------------------------------------------------------
__global__ __launch_bounds__(256)
void chunk_sum_kernel(const _Float16* __restrict__ kTh, const _Float16* __restrict__ vTh,
                      float* __restrict__ cbuf)
{
    const int ch = blockIdx.x, bh = blockIdx.y;
    const int t = threadIdx.x, l = t & 63, w = t >> 6;
    const int r15 = l & 15, kq = l >> 4;

    const _Float16* vbase = vTh + (size_t)bh * 64 * kN + ch * 64;
    const _Float16* kbase = kTh + (size_t)bh * 64 * kN + ch * 64;

    f16x8 av[2], bk[4][2];
    #pragma unroll
    for (int kk = 0; kk < 2; ++kk) {
        av[kk] = *(const f16x8*)(vbase + (size_t)(w * 16 + r15) * kN + kk * 32 + kq * 8);
        #pragma unroll
        for (int ni = 0; ni < 4; ++ni)
            bk[ni][kk] = *(const f16x8*)(kbase + (size_t)(ni * 16 + r15) * kN + kk * 32 + kq * 8);
    }
    floatx4 acc[4];
    #pragma unroll
    for (int ni = 0; ni < 4; ++ni) acc[ni] = (floatx4){0.f, 0.f, 0.f, 0.f};
    #pragma unroll
    for (int kk = 0; kk < 2; ++kk)
        #pragma unroll
        for (int ni = 0; ni < 4; ++ni)
            acc[ni] = __builtin_amdgcn_mfma_f32_16x16x32_f16(av[kk], bk[ni][kk], acc[ni], 0, 0, 0);

    float* out = cbuf + ((size_t)bh * NCH + ch) * CBSTRIDE;
    #pragma unroll
    for (int ni = 0; ni < 4; ++ni)
        #pragma unroll
        for (int r = 0; r < 4; ++r)
            out[(size_t)(w * 16 + kq * 4 + r) * 64 + ni * 16 + r15] = acc[ni][r];

    if (t < 64) {
        const _Float16* kp = kbase + (size_t)t * kN;
        float z = 0.f;
        #pragma unroll
        for (int j = 0; j < 8; ++j) {
            f16x8 v8 = *(const f16x8*)(kp + j * 8);
            #pragma unroll
            for (int u = 0; u < 8; ++u) z += (float)v8[u];
        }
        out[4096 + t] = z;
    }
}

// ---------------------------------------------------------------------------
// exclusive prefix over chunks; writes fp16 STpre (B-operand layout [e][d])
// and fp32 z_pre.  grid (17, BH), block 256.
// ---------------------------------------------------------------------------
__global__ __launch_bounds__(256)
void prefix_kernel(const float* __restrict__ cbuf, _Float16* __restrict__ spre16,
                   float* __restrict__ zpre)
{
    const int bh = blockIdx.y;
    const int i = blockIdx.x * 256 + threadIdx.x;
    if (i >= CBSTRIDE) return;
    const float* src = cbuf + (size_t)bh * NCH * CBSTRIDE + i;
    _Float16* dst = spre16 + (size_t)bh * NCH * CBSTRIDE + i;
    float* zp = zpre + (size_t)bh * NCH * 64;
    const bool isz = (i >= 4096);
    float vals[NCH];
    #pragma unroll
    for (int c = 0; c < NCH; ++c) vals[c] = src[(size_t)c * CBSTRIDE];
    float a = 0.f;
    #pragma unroll
    for (int c = 0; c < NCH; ++c) {
        dst[(size_t)c * CBSTRIDE] = (_Float16)a;
        if (isz) zp[c * 64 + (i - 4096)] = a;
        a += vals[c];
    }
}

// ---------------------------------------------------------------------------
// chunk_out (MFMA): scores = QK^T (masked) -> P fp16 in swizzled LDS,
// O = P V + Q STpre, den = rowsum(P) + q.z_pre, attn = O/den (fp16).
// grid (NCH, BH), block 256 (wave w = query rows w*16..w*16+15).
// ---------------------------------------------------------------------------
__global__ __launch_bounds__(256)
void chunk_out_kernel(const _Float16* __restrict__ qh, const _Float16* __restrict__ khb,
                      const _Float16* __restrict__ vTh, const _Float16* __restrict__ spre16,
                      const float* __restrict__ zpre, _Float16* __restrict__ attnh)
{
    const int ch = blockIdx.x, bh = blockIdx.y;
    const int t = threadIdx.x, l = t & 63, w = t >> 6;
    const int r15 = l & 15, kq = l >> 4;

    __shared__ _Float16 Plds[64 * 64];   // swizzled rows of 128 B
    __shared__ float denp[64];
    __shared__ float denf[64];

    const size_t rowbase = (size_t)bh * kN + ch * 64;

    // Phase 1: scores = Q K^T   (A rows = w*16 + r15, K-dim = d = 64)
    f16x8 aq[2], bk[4][2];
    #pragma unroll
    for (int kk = 0; kk < 2; ++kk) {
        aq[kk] = *(const f16x8*)(qh + (rowbase + w * 16 + r15) * 64 + kk * 32 + kq * 8);
        #pragma unroll
        for (int ni = 0; ni < 4; ++ni)
            bk[ni][kk] = *(const f16x8*)(khb + (rowbase + ni * 16 + r15) * 64 + kk * 32 + kq * 8);
    }
    floatx4 sacc[4];
    #pragma unroll
    for (int ni = 0; ni < 4; ++ni) sacc[ni] = (floatx4){0.f, 0.f, 0.f, 0.f};
    #pragma unroll
    for (int kk = 0; kk < 2; ++kk)
        #pragma unroll
        for (int ni = 0; ni < 4; ++ni)
            sacc[ni] = __builtin_amdgcn_mfma_f32_16x16x32_f16(aq[kk], bk[ni][kk], sacc[ni], 0, 0, 0);

    // mask (m <= qn), rowsum, P -> swizzled LDS fp16
    const int qrow = w * 16 + kq * 4;
    float psum[4] = {0.f, 0.f, 0.f, 0.f};
    #pragma unroll
    for (int ni = 0; ni < 4; ++ni) {
        const int m = ni * 16 + r15;
        #pragma unroll
        for (int r = 0; r < 4; ++r) {
            const int row = qrow + r;
            const float v = (m <= row) ? sacc[ni][r] : 0.f;
            psum[r] += v;
            const int byte = row * 128 + ((((unsigned)m >> 3) ^ (row & 7)) << 4) + (m & 7) * 2;
            *(_Float16*)((char*)Plds + byte) = (_Float16)v;
        }
    }
    #pragma unroll
    for (int r = 0; r < 4; ++r) {
        float p = psum[r];
        p += __shfl_xor(p, 1, 16);
        p += __shfl_xor(p, 2, 16);
        p += __shfl_xor(p, 4, 16);
        p += __shfl_xor(p, 8, 16);
        if (r15 == 0) denp[qrow + r] = p;
    }
    __syncthreads();

    // den finalize (64 threads)
    if (t < 64) {
        const _Float16* qp = qh + (rowbase + t) * 64;
        const float* zp = zpre + ((size_t)bh * NCH + ch) * 64;
        float s = denp[t];
        #pragma unroll
        for (int j = 0; j < 8; ++j) {
            f16x8 q8 = *(const f16x8*)(qp + j * 8);
            #pragma unroll
            for (int u = 0; u < 8; ++u) s += (float)q8[u] * zp[j * 8 + u];
        }
        denf[t] = 1.0f / s;
    }

    // Phase 2: O = P V + Q STpre
    f16x8 ap[2], bv[4][2], bs[4][2];
    #pragma unroll
    for (int km = 0; km < 2; ++km)
        ap[km] = *(const f16x8*)((char*)Plds + (w * 16 + r15) * 128 +
                                 (((km * 4 + kq) ^ (r15 & 7)) << 4));
    #pragma unroll
    for (int ni = 0; ni < 4; ++ni) {
        #pragma unroll
        for (int km = 0; km < 2; ++km)
            bv[ni][km] = *(const f16x8*)(vTh + ((size_t)bh * 64 + ni * 16 + r15) * kN +
                                         ch * 64 + km * 32 + kq * 8);
    }
    const _Float16* sp = spre16 + ((size_t)bh * NCH + ch) * CBSTRIDE;
    #pragma unroll
    for (int ni = 0; ni < 4; ++ni)
        #pragma unroll
        for (int kd = 0; kd < 2; ++kd)
            bs[ni][kd] = *(const f16x8*)(sp + (size_t)(ni * 16 + r15) * 64 + kd * 32 + kq * 8);

    floatx4 oacc[4];
    #pragma unroll
    for (int ni = 0; ni < 4; ++ni) oacc[ni] = (floatx4){0.f, 0.f, 0.f, 0.f};
    #pragma unroll
    for (int km = 0; km < 2; ++km)
        #pragma unroll
        for (int ni = 0; ni < 4; ++ni)
            oacc[ni] = __builtin_amdgcn_mfma_f32_16x16x32_f16(ap[km], bv[ni][km], oacc[ni], 0, 0, 0);
    #pragma unroll
    for (int kd = 0; kd < 2; ++kd)
        #pragma unroll
        for (int ni = 0; ni < 4; ++ni)
            oacc[ni] = __builtin_amdgcn_mfma_f32_16x16x32_f16(aq[kd], bs[ni][kd], oacc[ni], 0, 0, 0);
    __syncthreads();   // denf ready

    const int b = bh >> 3, h = bh & 7;
    #pragma unroll
    for (int ni = 0; ni < 4; ++ni) {
        const int e = ni * 16 + r15;
        #pragma unroll
        for (int r = 0; r < 4; ++r) {
            const int qn = qrow + r;
            const float ov = oacc[ni][r] * denf[qn];
            attnh[((size_t)(b * kN + ch * 64 + qn)) * 512 + h * 64 + e] = (_Float16)ov;
        }
    }
}

// ---------------------------------------------------------------------------
// out GEMM: out = attnh @ WoT^T + bo.  BM=BN=128, BK=64, 256 threads.
// 1-D grid of 128 blocks, bijective XCD swizzle.
// ---------------------------------------------------------------------------
__global__ __launch_bounds__(256)
void out_gemm_kernel(const _Float16* __restrict__ A,
                     const _Float16* __restrict__ BT,
                     const float* __restrict__ bo,
                     float* __restrict__ outf)
{
    constexpr int K = 512;
    __shared__ _Float16 As[128 * 64];
    __shared__ _Float16 Bs[128 * 64];

    // XCD-bijective swizzle: 128 blocks, 16 per XCD.
    const int bid = blockIdx.x;
    const int swz = (bid & 7) * 16 + (bid >> 3);
    const int bx = swz >> 5;            // 0..3 col-tile
    const int by = swz & 31;            // 0..31 row-tile

    const int t = threadIdx.x;
    const int l = t & 63;
    const int w = t >> 6;
    const int wm = w >> 1, wn = w & 1;
    const int m0 = by * 128;
    const int n0 = bx * 128;

    const int r15 = l & 15, kq = l >> 4, sw = r15 & 7;

    floatx4 acc[4][4];
    #pragma unroll
    for (int mi = 0; mi < 4; ++mi)
        #pragma unroll
        for (int ni = 0; ni < 4; ++ni)
            acc[mi][ni] = (floatx4){0.f, 0.f, 0.f, 0.f};

    const int srow  = t >> 3;
    const int sslot = t & 7;

    const char* Abase = (const char*)(A + (size_t)m0 * K);
    const char* Bbase = (const char*)(BT + (size_t)n0 * K);
    char* AsB = (char*)As;
    char* BsB = (char*)Bs;

    const char* ArdB = (const char*)As + (wm * 64 + r15) * 128;
    const char* BrdB = (const char*)Bs + (wn * 64 + r15) * 128;
    const int sw0 = ((kq ^ sw) << 4);
    const int sw1 = (((4 + kq) ^ sw) << 4);

    for (int k0 = 0; k0 < K; k0 += 64) {
        #pragma unroll
        for (int i = 0; i < 4; ++i) {
            const int row = i * 32 + srow;
            const int gsl = sslot ^ (row & 7);
            async_copy16(AsB + row * 128 + sslot * 16,
                         Abase + (size_t)row * (K * 2) + k0 * 2 + gsl * 16);
            async_copy16(BsB + row * 128 + sslot * 16,
                         Bbase + (size_t)row * (K * 2) + k0 * 2 + gsl * 16);
        }
        __syncthreads();

        f16x8 af[4][2], bf[4][2];
        #pragma unroll
        for (int i = 0; i < 4; ++i) {
            af[i][0] = *(const f16x8*)(ArdB + i * 2048 + sw0);
            af[i][1] = *(const f16x8*)(ArdB + i * 2048 + sw1);
            bf[i][0] = *(const f16x8*)(BrdB + i * 2048 + sw0);
            bf[i][1] = *(const f16x8*)(BrdB + i * 2048 + sw1);
        }
        #pragma unroll
        for (int kk = 0; kk < 2; ++kk)
            #pragma unroll
            for (int mi = 0; mi < 4; ++mi)
                #pragma unroll
                for (int ni = 0; ni < 4; ++ni)
                    acc[mi][ni] = __builtin_amdgcn_mfma_f32_16x16x32_f16(
                        af[mi][kk], bf[ni][kk], acc[mi][ni], 0, 0, 0);
        __syncthreads();
    }

    #pragma unroll
    for (int ni = 0; ni < 4; ++ni) {
        const int col = n0 + wn * 64 + ni * 16 + r15;
        const float bias = bo[col];
        #pragma unroll
        for (int mi = 0; mi < 4; ++mi) {
            const int row = m0 + wm * 64 + mi * 16 + kq * 4;
            #pragma unroll
            for (int r = 0; r < 4; ++r)
                outf[(size_t)(row + r) * 512 + col] = acc[mi][ni][r] + bias;
        }
    }
}

// ---------------------------------------------------------------------------
extern "C" void kernel_launch(void* const* d_in, const int* in_sizes, int n_in,
                              void* d_out, int out_size, void* d_ws, size_t ws_size,
                              hipStream_t stream)
{
    const float* x  = (const float*)d_in[0];
    const float* Wq = (const float*)d_in[1];
    const float* Wk = (const float*)d_in[2];
    const float* Wv = (const float*)d_in[3];
    const float* Wo = (const float*)d_in[4];
    const float* bo = (const float*)d_in[5];
    float* out = (float*)d_out;

    char* ws = (char*)d_ws;
    _Float16* qh     = (_Float16*)(ws + 0);          // 4,194,304 B [bh][n][64]
    _Float16* khb    = (_Float16*)(ws + 4194304);    // 4,194,304 B [bh][n][64]
    _Float16* kTh    = (_Float16*)(ws + 8388608);    // 4,194,304 B [bh][64][n]
    _Float16* vTh    = (_Float16*)(ws + 12582912);   // 4,194,304 B [bh][64][n]
    float*    cbuf   = (float*)(ws + 16777216);      // 8,519,680 B [bh][ch][4160] f32
    _Float16* spre16 = (_Float16*)(ws + 25296896);   // 4,259,840 B [bh][ch][4160] f16
    float*    zpre   = (float*)(ws + 29556736);      //   131,072 B [bh][ch][64] f32
    _Float16* WT     = (_Float16*)(ws + 29687808);   // 1,572,864 B [1536][512] f16
    _Float16* WoT    = (_Float16*)(ws + 31260672);   //   524,288 B [512][512] f16
    _Float16* attnh  = (_Float16*)(ws + 31784960);   // 4,194,304 B [4096][512] f16
    _Float16* xh     = (_Float16*)(ws + 35979264);   // 4,194,304 B [4096][512] f16

    prep_kernel<<<dim3(16, 16, 12), 256, 0, stream>>>(Wq, Wk, Wv, Wo, x, WT, WoT, xh);
    qkv_gemm_kernel<<<384, 256, 0, stream>>>(xh, WT, qh, khb, kTh, vTh);
    chunk_sum_kernel<<<dim3(NCH, kBH), 256, 0, stream>>>(kTh, vTh, cbuf);
    prefix_kernel<<<dim3(17, kBH), 256, 0, stream>>>(cbuf, spre16, zpre);
    chunk_out_kernel<<<dim3(NCH, kBH), 256, 0, stream>>>(
        qh, khb, vTh, spre16, zpre, attnh);
    out_gemm_kernel<<<128, 256, 0, stream>>>(attnh, WoT, bo, out);
}